// Round 1
// baseline (653.201 us; speedup 1.0000x reference)
//
#include <hip/hip_runtime.h>

// cLSTM fused single-step: h=c=c_target=0  =>
//   g5 = x[16384,1024] @ W5[1024, 5*1024] + b5   (gates i, it, z, o, d; f/ft dead)
//   epilogue: sigmoid/softplus/tanh -> 5 outputs [B,H] f32 each.
// bf16 MFMA GEMM (threshold 4.8e-2 permits), m97-style global_load_lds staging.

#define B_SZ 16384
#define H_SZ 1024
#define K_SZ 1024
#define BH ((size_t)B_SZ * H_SZ)
#define NGATE 5

typedef __bf16 bf16x8 __attribute__((ext_vector_type(8)));
typedef float f32x4 __attribute__((ext_vector_type(4)));

__device__ __forceinline__ unsigned short f2bf(float f) {
    unsigned int u = __float_as_uint(f);
    u += 0x7FFFu + ((u >> 16) & 1u);   // round-to-nearest-even
    return (unsigned short)(u >> 16);
}

__device__ __forceinline__ float sigm(float x) {
    return 1.f / (1.f + __expf(-x));
}
__device__ __forceinline__ float softplus_f(float x) {
    // log1p(exp(x)) = max(x,0) + log(1 + exp(-|x|)), arg of log in (1,2]
    return fmaxf(x, 0.f) + __logf(1.f + __expf(-fabsf(x)));
}
__device__ __forceinline__ float tanh_f(float x) {
    // cell in (-1,1) here; (e^{2x}-1)/(e^{2x}+1) is stable in that range
    float e = __expf(2.f * x);
    return (e - 1.f) / (e + 1.f);
}

// ---- pass 1a: x f32 -> bf16 (coalesced, 4 elems/thread) ----
__global__ void conv_x_kernel(const float* __restrict__ x, unsigned short* __restrict__ xb) {
    int i = blockIdx.x * blockDim.x + threadIdx.x;
    float4 v = ((const float4*)x)[i];
    ushort4 o;
    o.x = f2bf(v.x); o.y = f2bf(v.y); o.z = f2bf(v.z); o.w = f2bf(v.w);
    ((ushort4*)xb)[i] = o;
}

// ---- pass 1b: W[k,n] (k<1024 rows only) -> Wt[g][n][k] bf16, LDS-tiled transpose ----
__global__ void conv_w_kernel(const float* __restrict__ W0, const float* __restrict__ W1,
                              const float* __restrict__ W2, const float* __restrict__ W3,
                              const float* __restrict__ W4, unsigned short* __restrict__ wt) {
    const float* Ws[NGATE] = {W0, W1, W2, W3, W4};
    const float* W = Ws[blockIdx.z];
    __shared__ float tile[32][33];
    const int k0 = blockIdx.x * 32, n0 = blockIdx.y * 32;
    const int r = threadIdx.x >> 5, c = threadIdx.x & 31;
#pragma unroll
    for (int rr = 0; rr < 4; rr++) {
        // read coalesced along n
        tile[r + rr * 8][c] = W[(size_t)(k0 + r + rr * 8) * H_SZ + n0 + c];
    }
    __syncthreads();
    unsigned short* out = wt + (size_t)blockIdx.z * H_SZ * K_SZ;
#pragma unroll
    for (int rr = 0; rr < 4; rr++) {
        // write coalesced along k
        out[(size_t)(n0 + r + rr * 8) * K_SZ + k0 + c] = f2bf(tile[c][r + rr * 8]);
    }
}

// ---- pass 2: fused 5-gate GEMM + epilogue ----
// block tile 64(m) x 64(n), 4 waves (2x2), each wave 32x32 per gate.
// LDS: As[64][32] + Bs[5][64 n][32 k] bf16 = 24 KB, staged via global_load_lds w=16.
__global__ __launch_bounds__(256, 2) void fused_clstm_kernel(
    const unsigned short* __restrict__ xb,   // [16384][1024] bf16
    const unsigned short* __restrict__ wt,   // [5][1024 n][1024 k] bf16
    const float* __restrict__ bi, const float* __restrict__ bit_,
    const float* __restrict__ bz, const float* __restrict__ bo,
    const float* __restrict__ bd,
    const float* __restrict__ t, const float* __restrict__ last_t,
    float* __restrict__ out)
{
    __shared__ unsigned short smem[(1 + NGATE) * 2048];  // chunk c -> smem[c*512 ..]

    const int tid  = threadIdx.x;
    const int wave = tid >> 6;
    const int lane = tid & 63;
    const int quad = lane >> 4;
    const int l16  = lane & 15;
    const int wm   = wave >> 1;      // 0..1
    const int wn   = wave & 1;       // 0..1
    const int m0   = blockIdx.y * 64;
    const int n0   = blockIdx.x * 64;

    f32x4 acc[NGATE][2][2];
#pragma unroll
    for (int g = 0; g < NGATE; g++)
#pragma unroll
        for (int mf = 0; mf < 2; mf++)
#pragma unroll
            for (int nf = 0; nf < 2; nf++)
                acc[g][mf][nf] = (f32x4){0.f, 0.f, 0.f, 0.f};

    const int srow = lane >> 2;        // 0..15 (row within 16-row chunk)
    const int scol = (lane & 3) * 8;   // 0,8,16,24 (k-offset, 8 bf16 = 16 B)

    for (int k0 = 0; k0 < K_SZ; k0 += 32) {
        __syncthreads();   // previous tile fully consumed
#pragma unroll
        for (int i = 0; i < 6; i++) {
            const int c = wave * 6 + i;    // 0..23: 0-3 = A, 4.. = B gate (c-4)/4
            const unsigned short* gsrc;
            if (c < 4) {
                gsrc = xb + (size_t)(m0 + c * 16 + srow) * K_SZ + k0 + scol;
            } else {
                const int g = (c - 4) >> 2, q = (c - 4) & 3;
                gsrc = wt + (size_t)g * H_SZ * K_SZ
                          + (size_t)(n0 + q * 16 + srow) * K_SZ + k0 + scol;
            }
            __builtin_amdgcn_global_load_lds(
                (const __attribute__((address_space(1))) unsigned int*)gsrc,
                (__attribute__((address_space(3))) unsigned int*)(&smem[c * 512 + lane * 8]),
                16, 0, 0);
        }
        __syncthreads();   // drains vmcnt before barrier -> LDS visible

        // A frags: A[m = l16][k = quad*8+j], contiguous k in LDS
        bf16x8 a0 = *(const bf16x8*)(&smem[(wm * 32      + l16) * 32 + quad * 8]);
        bf16x8 a1 = *(const bf16x8*)(&smem[(wm * 32 + 16 + l16) * 32 + quad * 8]);
#pragma unroll
        for (int g = 0; g < NGATE; g++) {
            const unsigned short* bs = &smem[(1 + g) * 2048];
            // B frags: B[k = quad*8+j][n = l16] from [n][k]-major LDS
            bf16x8 b0 = *(const bf16x8*)(&bs[(wn * 32      + l16) * 32 + quad * 8]);
            bf16x8 b1 = *(const bf16x8*)(&bs[(wn * 32 + 16 + l16) * 32 + quad * 8]);
            acc[g][0][0] = __builtin_amdgcn_mfma_f32_16x16x32_bf16(a0, b0, acc[g][0][0], 0, 0, 0);
            acc[g][1][0] = __builtin_amdgcn_mfma_f32_16x16x32_bf16(a1, b0, acc[g][1][0], 0, 0, 0);
            acc[g][0][1] = __builtin_amdgcn_mfma_f32_16x16x32_bf16(a0, b1, acc[g][0][1], 0, 0, 0);
            acc[g][1][1] = __builtin_amdgcn_mfma_f32_16x16x32_bf16(a1, b1, acc[g][1][1], 0, 0, 0);
        }
    }

    // ---- epilogue: C/D layout col = l16, row = quad*4 + reg ----
    const float* biasp[NGATE] = {bi, bit_, bz, bo, bd};
    float bv[NGATE][2];
#pragma unroll
    for (int g = 0; g < NGATE; g++)
#pragma unroll
        for (int nf = 0; nf < 2; nf++)
            bv[g][nf] = biasp[g][n0 + wn * 32 + nf * 16 + l16];

#pragma unroll
    for (int mf = 0; mf < 2; mf++) {
#pragma unroll
        for (int r = 0; r < 4; r++) {
            const int brow = m0 + wm * 32 + mf * 16 + quad * 4 + r;
            const float dt = t[brow] - last_t[brow];
#pragma unroll
            for (int nf = 0; nf < 2; nf++) {
                const int ncol = n0 + wn * 32 + nf * 16 + l16;
                const float gi  = acc[0][mf][nf][r] + bv[0][nf];
                const float git = acc[1][mf][nf][r] + bv[1][nf];
                const float gz  = acc[2][mf][nf][r] + bv[2][nf];
                const float go  = acc[3][mf][nf][r] + bv[3][nf];
                const float gd  = acc[4][mf][nf][r] + bv[4][nf];

                const float gate_i  = sigm(gi);
                const float gate_it = sigm(git);
                const float z       = 2.f * sigm(gz) - 1.f;
                const float gate_o  = sigm(go);
                const float delta   = softplus_f(gd);

                const float c_n  = gate_i  * z;     // gate_f * 0 + gate_i * z
                const float ct_n = gate_it * z;
                const float cell = ct_n + (c_n - ct_n) * __expf(-delta * dt);
                const float h_n  = gate_o * tanh_f(cell);

                const size_t idx = (size_t)brow * H_SZ + ncol;
                out[idx]          = h_n;
                out[BH + idx]     = c_n;
                out[2 * BH + idx] = ct_n;
                out[3 * BH + idx] = gate_o;
                out[4 * BH + idx] = delta;
            }
        }
    }
}

extern "C" void kernel_launch(void* const* d_in, const int* in_sizes, int n_in,
                              void* d_out, int out_size, void* d_ws, size_t ws_size,
                              hipStream_t stream) {
    const float* x      = (const float*)d_in[0];
    // d_in[1] = n_id (unused by reference math)
    const float* t      = (const float*)d_in[2];
    const float* last_t = (const float*)d_in[3];
    const float* Wi  = (const float*)d_in[4];
    const float* bi  = (const float*)d_in[5];
    const float* Wit = (const float*)d_in[6];
    const float* bit_= (const float*)d_in[7];
    // d_in[8..11] = Wf, bf, Wft, bft : dead (multiply zero state)
    const float* Wz  = (const float*)d_in[12];
    const float* bz  = (const float*)d_in[13];
    const float* Wo  = (const float*)d_in[14];
    const float* bo  = (const float*)d_in[15];
    const float* Wd  = (const float*)d_in[16];
    const float* bd  = (const float*)d_in[17];

    unsigned short* xb = (unsigned short*)d_ws;                 // 32 MiB
    unsigned short* wt = xb + (size_t)B_SZ * K_SZ;              // + 10 MiB (=42 MiB total)

    conv_x_kernel<<<(B_SZ * K_SZ / 4) / 256, 256, 0, stream>>>(x, xb);

    dim3 gw(32, 32, NGATE);
    conv_w_kernel<<<gw, 256, 0, stream>>>(Wi, Wit, Wz, Wo, Wd, wt);

    dim3 gm(H_SZ / 64, B_SZ / 64);   // (16, 256)
    fused_clstm_kernel<<<gm, 256, 0, stream>>>(xb, wt, bi, bit_, bz, bo, bd,
                                               t, last_t, (float*)d_out);
}

// Round 2
// 608.979 us; speedup vs baseline: 1.0726x; 1.0726x over previous
//
#include <hip/hip_runtime.h>

// cLSTM fused single-step: h=c=c_target=0  =>
//   g5 = x[16384,1024] @ W5[1024, 5*1024] + b5   (gates i, it, z, o, d; f/ft dead)
//   epilogue: sigmoid/softplus/tanh -> 5 outputs [B,H] f32 each.
// R2: 128(m)x64(n) block tile, 4 waves, 40 MFMA : 14 ds_read : 7 glds per wave/k-step.
//     Staged L2 traffic 3.2 GB -> 1.83 GB; 2 blocks/CU for cross-block barrier overlap.

#define B_SZ 16384
#define H_SZ 1024
#define K_SZ 1024
#define BH ((size_t)B_SZ * H_SZ)
#define NGATE 5

typedef __bf16 bf16x8 __attribute__((ext_vector_type(8)));
typedef float f32x4 __attribute__((ext_vector_type(4)));

__device__ __forceinline__ unsigned short f2bf(float f) {
    unsigned int u = __float_as_uint(f);
    u += 0x7FFFu + ((u >> 16) & 1u);   // round-to-nearest-even
    return (unsigned short)(u >> 16);
}

__device__ __forceinline__ float rcp_fast(float x) { return __builtin_amdgcn_rcpf(x); }
__device__ __forceinline__ float sigm(float x) { return rcp_fast(1.f + __expf(-x)); }
__device__ __forceinline__ float softplus_f(float x) {
    return fmaxf(x, 0.f) + __logf(1.f + __expf(-fabsf(x)));
}
__device__ __forceinline__ float tanh_f(float x) {
    float e = __expf(2.f * x);          // cell in (-1,1): stable
    return (e - 1.f) * rcp_fast(e + 1.f);
}

// ---- pass 1a: x f32 -> bf16 (coalesced, 4 elems/thread) ----
__global__ void conv_x_kernel(const float* __restrict__ x, unsigned short* __restrict__ xb) {
    int i = blockIdx.x * blockDim.x + threadIdx.x;
    float4 v = ((const float4*)x)[i];
    ushort4 o;
    o.x = f2bf(v.x); o.y = f2bf(v.y); o.z = f2bf(v.z); o.w = f2bf(v.w);
    ((ushort4*)xb)[i] = o;
}

// ---- pass 1b: W[k,n] (first 1024 k-rows only) -> Wt[g][n][k] bf16 ----
// 64x64 tile; coalesced 256B row loads; ushort4 (8B/lane) writes.
__global__ void conv_w_kernel(const float* __restrict__ W0, const float* __restrict__ W1,
                              const float* __restrict__ W2, const float* __restrict__ W3,
                              const float* __restrict__ W4, unsigned short* __restrict__ wt) {
    const float* Ws[NGATE] = {W0, W1, W2, W3, W4};
    const float* W = Ws[blockIdx.z];
    __shared__ float tile[64][65];
    const int k0 = blockIdx.x * 64, n0 = blockIdx.y * 64;
    const int tid = threadIdx.x;
    {
        const int kk = tid >> 6, nn = tid & 63;
#pragma unroll
        for (int rr = 0; rr < 16; rr++) {
            const int row = kk * 16 + rr;
            tile[row][nn] = W[(size_t)(k0 + row) * H_SZ + n0 + nn];
        }
    }
    __syncthreads();
    unsigned short* out = wt + (size_t)blockIdx.z * H_SZ * K_SZ;
    {
        const int nrow = tid >> 2, kq = (tid & 3) * 16;
#pragma unroll
        for (int j = 0; j < 4; j++) {
            const int k = kq + j * 4;
            ushort4 v;
            v.x = f2bf(tile[k + 0][nrow]);
            v.y = f2bf(tile[k + 1][nrow]);
            v.z = f2bf(tile[k + 2][nrow]);
            v.w = f2bf(tile[k + 3][nrow]);
            *(ushort4*)&out[(size_t)(n0 + nrow) * K_SZ + k0 + k] = v;
        }
    }
}

// ---- pass 2: fused 5-gate GEMM + epilogue ----
// block tile 128(m) x 64(n), 4 waves (wm 0..1 x wn 0..1), each wave 64x32 per gate.
// LDS: A[128][32] + B[5][64][32] bf16 = 28 KB, staged via global_load_lds w=16.
__global__ __launch_bounds__(256, 2) void fused_clstm_kernel(
    const unsigned short* __restrict__ xb,   // [16384][1024] bf16
    const unsigned short* __restrict__ wt,   // [5][1024 n][1024 k] bf16
    const float* __restrict__ bi, const float* __restrict__ bit_,
    const float* __restrict__ bz, const float* __restrict__ bo,
    const float* __restrict__ bd,
    const float* __restrict__ t, const float* __restrict__ last_t,
    float* __restrict__ out)
{
    __shared__ unsigned short smem[28 * 512];  // chunk c (1 KB) -> smem[c*512 ..]

    const int tid  = threadIdx.x;
    const int wave = tid >> 6;
    const int lane = tid & 63;
    const int quad = lane >> 4;
    const int l16  = lane & 15;
    const int wm   = wave >> 1;      // 0..1 -> m-half (64 rows)
    const int wn   = wave & 1;       // 0..1 -> n-half (32 cols)
    const int m0   = blockIdx.y * 128;
    const int n0   = blockIdx.x * 64;

    f32x4 acc[NGATE][4][2];
#pragma unroll
    for (int g = 0; g < NGATE; g++)
#pragma unroll
        for (int mf = 0; mf < 4; mf++)
#pragma unroll
            for (int nf = 0; nf < 2; nf++)
                acc[g][mf][nf] = (f32x4){0.f, 0.f, 0.f, 0.f};

    const int srow = lane >> 2;        // 0..15 (row within 16-row chunk)
    const int scol = (lane & 3) * 8;   // k-offset: 8 bf16 = 16 B

    for (int k0 = 0; k0 < K_SZ; k0 += 32) {
        __syncthreads();   // previous tile fully consumed
#pragma unroll
        for (int i = 0; i < 7; i++) {
            const int c = wave * 7 + i;    // 0..27: 0-7 = A (128 rows), 8.. = B gate (c-8)/4
            const unsigned short* gsrc;
            if (c < 8) {
                gsrc = xb + (size_t)(m0 + c * 16 + srow) * K_SZ + k0 + scol;
            } else {
                const int g = (c - 8) >> 2, q = (c - 8) & 3;
                gsrc = wt + (size_t)g * H_SZ * K_SZ
                          + (size_t)(n0 + q * 16 + srow) * K_SZ + k0 + scol;
            }
            __builtin_amdgcn_global_load_lds(
                (const __attribute__((address_space(1))) unsigned int*)gsrc,
                (__attribute__((address_space(3))) unsigned int*)(&smem[c * 512 + lane * 8]),
                16, 0, 0);
        }
        __syncthreads();   // drains vmcnt -> LDS visible

        // A frags: A[m = l16][k = quad*8+j]; A rows 0..127 at smem[m*32]
        bf16x8 a[4];
#pragma unroll
        for (int mf = 0; mf < 4; mf++)
            a[mf] = *(const bf16x8*)(&smem[(wm * 64 + mf * 16 + l16) * 32 + quad * 8]);
#pragma unroll
        for (int g = 0; g < NGATE; g++) {
            const unsigned short* bs = &smem[(8 + g * 4) * 512];
            bf16x8 b0 = *(const bf16x8*)(&bs[(wn * 32      + l16) * 32 + quad * 8]);
            bf16x8 b1 = *(const bf16x8*)(&bs[(wn * 32 + 16 + l16) * 32 + quad * 8]);
#pragma unroll
            for (int mf = 0; mf < 4; mf++) {
                acc[g][mf][0] = __builtin_amdgcn_mfma_f32_16x16x32_bf16(a[mf], b0, acc[g][mf][0], 0, 0, 0);
                acc[g][mf][1] = __builtin_amdgcn_mfma_f32_16x16x32_bf16(a[mf], b1, acc[g][mf][1], 0, 0, 0);
            }
        }
    }

    // ---- epilogue: C/D layout col = l16, row = quad*4 + reg ----
    const float* biasp[NGATE] = {bi, bit_, bz, bo, bd};
    float bv[NGATE][2];
#pragma unroll
    for (int g = 0; g < NGATE; g++)
#pragma unroll
        for (int nf = 0; nf < 2; nf++)
            bv[g][nf] = biasp[g][n0 + wn * 32 + nf * 16 + l16];

#pragma unroll
    for (int mf = 0; mf < 4; mf++) {
#pragma unroll
        for (int r = 0; r < 4; r++) {
            const int brow = m0 + wm * 64 + mf * 16 + quad * 4 + r;
            const float dt = t[brow] - last_t[brow];
#pragma unroll
            for (int nf = 0; nf < 2; nf++) {
                const int ncol = n0 + wn * 32 + nf * 16 + l16;
                const float gi  = acc[0][mf][nf][r] + bv[0][nf];
                const float git = acc[1][mf][nf][r] + bv[1][nf];
                const float gz  = acc[2][mf][nf][r] + bv[2][nf];
                const float go  = acc[3][mf][nf][r] + bv[3][nf];
                const float gd  = acc[4][mf][nf][r] + bv[4][nf];

                const float gate_i  = sigm(gi);
                const float gate_it = sigm(git);
                const float z       = 2.f * sigm(gz) - 1.f;
                const float gate_o  = sigm(go);
                const float delta   = softplus_f(gd);

                const float c_n  = gate_i  * z;     // gate_f * 0 + gate_i * z
                const float ct_n = gate_it * z;
                const float cell = ct_n + (c_n - ct_n) * __expf(-delta * dt);
                const float h_n  = gate_o * tanh_f(cell);

                const size_t idx = (size_t)brow * H_SZ + ncol;
                out[idx]          = h_n;
                out[BH + idx]     = c_n;
                out[2 * BH + idx] = ct_n;
                out[3 * BH + idx] = gate_o;
                out[4 * BH + idx] = delta;
            }
        }
    }
}

extern "C" void kernel_launch(void* const* d_in, const int* in_sizes, int n_in,
                              void* d_out, int out_size, void* d_ws, size_t ws_size,
                              hipStream_t stream) {
    const float* x      = (const float*)d_in[0];
    // d_in[1] = n_id (unused by reference math)
    const float* t      = (const float*)d_in[2];
    const float* last_t = (const float*)d_in[3];
    const float* Wi  = (const float*)d_in[4];
    const float* bi  = (const float*)d_in[5];
    const float* Wit = (const float*)d_in[6];
    const float* bit_= (const float*)d_in[7];
    // d_in[8..11] = Wf, bf, Wft, bft : dead (multiply zero state)
    const float* Wz  = (const float*)d_in[12];
    const float* bz  = (const float*)d_in[13];
    const float* Wo  = (const float*)d_in[14];
    const float* bo  = (const float*)d_in[15];
    const float* Wd  = (const float*)d_in[16];
    const float* bd  = (const float*)d_in[17];

    unsigned short* xb = (unsigned short*)d_ws;                 // 32 MiB
    unsigned short* wt = xb + (size_t)B_SZ * K_SZ;              // + 10 MiB (=42 MiB total)

    conv_x_kernel<<<(B_SZ * K_SZ / 4) / 256, 256, 0, stream>>>(x, xb);

    dim3 gw(16, 16, NGATE);
    conv_w_kernel<<<gw, 256, 0, stream>>>(Wi, Wit, Wz, Wo, Wd, wt);

    dim3 gm(H_SZ / 64, B_SZ / 128);   // (16, 128)
    fused_clstm_kernel<<<gm, 256, 0, stream>>>(xb, wt, bi, bit_, bz, bo, bd,
                                               t, last_t, (float*)d_out);
}